// Round 1
// baseline (1626.969 us; speedup 1.0000x reference)
//
#include <hip/hip_runtime.h>
#include <hip/hip_bf16.h>
#include <stdint.h>

#define IN_DIM    256
#define OUT_DIM   256
#define NUM_HEADS 4
#define HEAD_DIM  64
#define N_SRC     100000
#define N_DST     50000
#define N_EDGES   300000

typedef __attribute__((ext_vector_type(8))) short v8s;   // 8 x bf16 bits
typedef __attribute__((ext_vector_type(4))) float v4f;   // MFMA accumulator

__device__ __forceinline__ unsigned short f2bf(float f) {
    unsigned u = __float_as_uint(f);
    unsigned r = (u + 0x7FFFu + ((u >> 16) & 1u)) >> 16;   // RNE
    return (unsigned short)r;
}
__device__ __forceinline__ float bf2f(unsigned short s) {
    return __uint_as_float(((unsigned)s) << 16);
}

// ---------------------------------------------------------------- W -> bf16
__global__ void cvt_w_kernel(const float* __restrict__ Wq,
                             const float* __restrict__ Wk,
                             const float* __restrict__ Wv,
                             unsigned short* __restrict__ Wb) {
    int m = blockIdx.y;
    const float* src = (m == 0) ? Wq : (m == 1) ? Wk : Wv;
    int i = blockIdx.x * 256 + threadIdx.x;   // 0..65535
    Wb[m * 65536 + i] = f2bf(src[i]);
}

// ------------------------------------------------- fused Q/K/V projections
// One wave computes a 16x64 output tile over full K=256.
// A-frag: h[m=lane&15][k0 + quad*8 + j] (fp32 -> bf16 on the fly)
// B-frag: W[n=lane&15+...][k0 + quad*8 + j] (pre-converted bf16, contiguous 16B)
// C/D:    col = lane&15 (+t*16), row = quad*4 + reg
__global__ __launch_bounds__(256) void proj_kernel(
    const float* __restrict__ h_src, const float* __restrict__ h_dst,
    const unsigned short* __restrict__ Wb,
    const float* __restrict__ bq, const float* __restrict__ bk,
    const float* __restrict__ bv,
    unsigned short* __restrict__ Q, unsigned short* __restrict__ K,
    unsigned short* __restrict__ V) {

    int z = blockIdx.z;
    const float* A; const unsigned short* W; const float* bias;
    unsigned short* Out; int M;
    if (z == 0)      { A = h_dst; W = Wb;           bias = bq; Out = Q; M = N_DST; }
    else if (z == 1) { A = h_src; W = Wb + 65536;   bias = bk; Out = K; M = N_SRC; }
    else             { A = h_src; W = Wb + 131072;  bias = bv; Out = V; M = N_SRC; }

    int wave = threadIdx.x >> 6;
    int lane = threadIdx.x & 63;
    int mbase = blockIdx.x * 64 + wave * 16;
    if (mbase >= M) return;
    int nbase = blockIdx.y * 64;
    int lm = lane & 15, quad = lane >> 4;

    int arow = mbase + lm;
    if (arow >= M) arow = M - 1;               // clamp; store is guarded
    const float* aptr = A + (size_t)arow * 256 + quad * 8;

    v4f acc0 = {0,0,0,0}, acc1 = {0,0,0,0}, acc2 = {0,0,0,0}, acc3 = {0,0,0,0};

#pragma unroll
    for (int k0 = 0; k0 < 256; k0 += 32) {
        const float4* ap = (const float4*)(aptr + k0);
        float4 a0 = ap[0], a1 = ap[1];
        v8s af;
        af[0] = (short)f2bf(a0.x); af[1] = (short)f2bf(a0.y);
        af[2] = (short)f2bf(a0.z); af[3] = (short)f2bf(a0.w);
        af[4] = (short)f2bf(a1.x); af[5] = (short)f2bf(a1.y);
        af[6] = (short)f2bf(a1.z); af[7] = (short)f2bf(a1.w);

        const unsigned short* wbase = W + k0 + quad * 8;
        v8s b0 = *(const v8s*)(wbase + (size_t)(nbase +  0 + lm) * 256);
        v8s b1 = *(const v8s*)(wbase + (size_t)(nbase + 16 + lm) * 256);
        v8s b2 = *(const v8s*)(wbase + (size_t)(nbase + 32 + lm) * 256);
        v8s b3 = *(const v8s*)(wbase + (size_t)(nbase + 48 + lm) * 256);

        acc0 = __builtin_amdgcn_mfma_f32_16x16x32_bf16(af, b0, acc0, 0, 0, 0);
        acc1 = __builtin_amdgcn_mfma_f32_16x16x32_bf16(af, b1, acc1, 0, 0, 0);
        acc2 = __builtin_amdgcn_mfma_f32_16x16x32_bf16(af, b2, acc2, 0, 0, 0);
        acc3 = __builtin_amdgcn_mfma_f32_16x16x32_bf16(af, b3, acc3, 0, 0, 0);
    }

#pragma unroll
    for (int t = 0; t < 4; t++) {
        int col = nbase + t * 16 + lm;
        float bcol = bias[col];
        v4f acc = (t == 0) ? acc0 : (t == 1) ? acc1 : (t == 2) ? acc2 : acc3;
#pragma unroll
        for (int r = 0; r < 4; r++) {
            int row = mbase + quad * 4 + r;
            if (row < M) Out[(size_t)row * 256 + col] = f2bf(acc[r] + bcol);
        }
    }
}

// ------------------------------------------------------- per-edge scores
// 64 lanes per edge; lane reads 4 contiguous bf16 of K[src] and Q[dst];
// head = lane>>4; butterfly-reduce within 16-lane groups.
__global__ __launch_bounds__(256) void score_kernel(
    const int* __restrict__ src_idx, const int* __restrict__ dst_idx,
    const unsigned short* __restrict__ K, const unsigned short* __restrict__ Q,
    float* __restrict__ score, unsigned* __restrict__ segmax) {

    int wave = threadIdx.x >> 6, lane = threadIdx.x & 63;
    int e = blockIdx.x * 4 + wave;
    if (e >= N_EDGES) return;
    int s = src_idx[e], d = dst_idx[e];

    ushort4 kv = *((const ushort4*)(K + (size_t)s * 256) + lane);
    ushort4 qv = *((const ushort4*)(Q + (size_t)d * 256) + lane);
    float p = bf2f(kv.x) * bf2f(qv.x) + bf2f(kv.y) * bf2f(qv.y) +
              bf2f(kv.z) * bf2f(qv.z) + bf2f(kv.w) * bf2f(qv.w);
    p += __shfl_xor(p, 1, 64);
    p += __shfl_xor(p, 2, 64);
    p += __shfl_xor(p, 4, 64);
    p += __shfl_xor(p, 8, 64);
    p *= 0.125f;                                  // 1/sqrt(64)

    if ((lane & 15) == 0) {
        int h = lane >> 4;
        score[(size_t)e * 4 + h] = p;
        unsigned key = __float_as_uint(p);
        key = (key & 0x80000000u) ? ~key : (key | 0x80000000u); // order-preserving
        atomicMax(&segmax[d * 4 + h], key);
    }
}

// ------------------------------------------------------ exp + segment sum
__global__ void exp_kernel(const int* __restrict__ dst_idx,
                           float* __restrict__ score,
                           const unsigned* __restrict__ segmax,
                           float* __restrict__ segsum) {
    int i = blockIdx.x * 256 + threadIdx.x;
    if (i >= N_EDGES * 4) return;
    int e = i >> 2, h = i & 3;
    int d = dst_idx[e];
    unsigned key = segmax[d * 4 + h];
    float m = (key & 0x80000000u) ? __uint_as_float(key ^ 0x80000000u)
                                  : __uint_as_float(~key);
    float ex = __expf(score[i] - m);
    score[i] = ex;                                // in-place: now holds exp
    atomicAdd(&segsum[d * 4 + h], ex);
}

// ------------------------------------------------- weighted-V aggregation
__global__ __launch_bounds__(256) void agg_kernel(
    const int* __restrict__ src_idx, const int* __restrict__ dst_idx,
    const unsigned short* __restrict__ V, const float* __restrict__ score,
    const float* __restrict__ segsum, float* __restrict__ out) {

    int wave = threadIdx.x >> 6, lane = threadIdx.x & 63;
    int e = blockIdx.x * 4 + wave;
    if (e >= N_EDGES) return;
    int s = src_idx[e], d = dst_idx[e];
    int h = lane >> 4;

    float a = score[(size_t)e * 4 + h] / segsum[d * 4 + h];
    ushort4 vv = *((const ushort4*)(V + (size_t)s * 256) + lane);
    float* op = out + (size_t)d * 256 + lane * 4;
    atomicAdd(op + 0, bf2f(vv.x) * a);
    atomicAdd(op + 1, bf2f(vv.y) * a);
    atomicAdd(op + 2, bf2f(vv.z) * a);
    atomicAdd(op + 3, bf2f(vv.w) * a);
}

// --------------------------------------------------------------- launcher
extern "C" void kernel_launch(void* const* d_in, const int* in_sizes, int n_in,
                              void* d_out, int out_size, void* d_ws, size_t ws_size,
                              hipStream_t stream) {
    const float* h_src   = (const float*)d_in[0];
    const float* h_dst   = (const float*)d_in[1];
    const int*   src_idx = (const int*)d_in[2];
    const int*   dst_idx = (const int*)d_in[3];
    const float* Wq      = (const float*)d_in[4];
    const float* bq      = (const float*)d_in[5];
    const float* Wk      = (const float*)d_in[6];
    const float* bk      = (const float*)d_in[7];
    const float* Wv      = (const float*)d_in[8];
    const float* bv      = (const float*)d_in[9];
    float* out = (float*)d_out;

    // Workspace layout (256B-aligned)
    char* ws = (char*)d_ws;
    size_t off = 0;
    auto take = [&](size_t bytes) { char* p = ws + off; off = (off + bytes + 255) & ~(size_t)255; return p; };
    unsigned short* Q      = (unsigned short*)take((size_t)N_DST * 256 * 2);   // 25.6 MB
    unsigned short* K      = (unsigned short*)take((size_t)N_SRC * 256 * 2);   // 51.2 MB
    unsigned short* V      = (unsigned short*)take((size_t)N_SRC * 256 * 2);   // 51.2 MB
    unsigned short* Wb     = (unsigned short*)take((size_t)3 * 65536 * 2);     // 0.4 MB
    float*          score  = (float*)take((size_t)N_EDGES * 4 * 4);            // 4.8 MB
    unsigned*       segmax = (unsigned*)take((size_t)N_DST * 4 * 4);           // 0.8 MB
    float*          segsum = (float*)take((size_t)N_DST * 4 * 4);              // 0.8 MB
    (void)ws_size; (void)in_sizes; (void)n_in; (void)out_size;

    // Zero accumulators (0 uint key == -inf sentinel for segmax)
    hipMemsetAsync(out, 0, (size_t)N_DST * 256 * 4, stream);
    hipMemsetAsync(segmax, 0, (size_t)N_DST * 4 * 4, stream);
    hipMemsetAsync(segsum, 0, (size_t)N_DST * 4 * 4, stream);

    cvt_w_kernel<<<dim3(256, 3), 256, 0, stream>>>(Wq, Wk, Wv, Wb);

    // 64 rows x 64 cols per block; grid.x covers max(M)=100000 rows
    proj_kernel<<<dim3((N_SRC + 63) / 64, 4, 3), 256, 0, stream>>>(
        h_src, h_dst, Wb, bq, bk, bv, Q, K, V);

    score_kernel<<<N_EDGES / 4, 256, 0, stream>>>(src_idx, dst_idx, K, Q, score, segmax);

    exp_kernel<<<(N_EDGES * 4 + 255) / 256, 256, 0, stream>>>(dst_idx, score, segmax, segsum);

    agg_kernel<<<N_EDGES / 4, 256, 0, stream>>>(src_idx, dst_idx, V, score, segsum, out);
}

// Round 2
// 822.880 us; speedup vs baseline: 1.9772x; 1.9772x over previous
//
#include <hip/hip_runtime.h>
#include <hip/hip_bf16.h>
#include <stdint.h>

#define IN_DIM    256
#define OUT_DIM   256
#define NUM_HEADS 4
#define HEAD_DIM  64
#define N_SRC     100000
#define N_DST     50000
#define N_EDGES   300000

typedef __attribute__((ext_vector_type(8))) short v8s;   // 8 x bf16 bits
typedef __attribute__((ext_vector_type(4))) float v4f;   // MFMA accumulator

__device__ __forceinline__ unsigned short f2bf(float f) {
    unsigned u = __float_as_uint(f);
    unsigned r = (u + 0x7FFFu + ((u >> 16) & 1u)) >> 16;   // RNE
    return (unsigned short)r;
}
__device__ __forceinline__ float bf2f(unsigned short s) {
    return __uint_as_float(((unsigned)s) << 16);
}

// ---------------------------------------------------------------- W -> bf16
__global__ void cvt_w_kernel(const float* __restrict__ Wq,
                             const float* __restrict__ Wk,
                             const float* __restrict__ Wv,
                             unsigned short* __restrict__ Wb) {
    int m = blockIdx.y;
    const float* src = (m == 0) ? Wq : (m == 1) ? Wk : Wv;
    int i = blockIdx.x * 256 + threadIdx.x;   // 0..65535
    Wb[m * 65536 + i] = f2bf(src[i]);
}

// ------------------------------------------------- fused Q/K/V projections
__global__ __launch_bounds__(256) void proj_kernel(
    const float* __restrict__ h_src, const float* __restrict__ h_dst,
    const unsigned short* __restrict__ Wb,
    const float* __restrict__ bq, const float* __restrict__ bk,
    const float* __restrict__ bv,
    unsigned short* __restrict__ Q, unsigned short* __restrict__ K,
    unsigned short* __restrict__ V) {

    int z = blockIdx.z;
    const float* A; const unsigned short* W; const float* bias;
    unsigned short* Out; int M;
    if (z == 0)      { A = h_dst; W = Wb;           bias = bq; Out = Q; M = N_DST; }
    else if (z == 1) { A = h_src; W = Wb + 65536;   bias = bk; Out = K; M = N_SRC; }
    else             { A = h_src; W = Wb + 131072;  bias = bv; Out = V; M = N_SRC; }

    int wave = threadIdx.x >> 6;
    int lane = threadIdx.x & 63;
    int mbase = blockIdx.x * 64 + wave * 16;
    if (mbase >= M) return;
    int nbase = blockIdx.y * 64;
    int lm = lane & 15, quad = lane >> 4;

    int arow = mbase + lm;
    if (arow >= M) arow = M - 1;               // clamp; store is guarded
    const float* aptr = A + (size_t)arow * 256 + quad * 8;

    v4f acc0 = {0,0,0,0}, acc1 = {0,0,0,0}, acc2 = {0,0,0,0}, acc3 = {0,0,0,0};

#pragma unroll
    for (int k0 = 0; k0 < 256; k0 += 32) {
        const float4* ap = (const float4*)(aptr + k0);
        float4 a0 = ap[0], a1 = ap[1];
        v8s af;
        af[0] = (short)f2bf(a0.x); af[1] = (short)f2bf(a0.y);
        af[2] = (short)f2bf(a0.z); af[3] = (short)f2bf(a0.w);
        af[4] = (short)f2bf(a1.x); af[5] = (short)f2bf(a1.y);
        af[6] = (short)f2bf(a1.z); af[7] = (short)f2bf(a1.w);

        const unsigned short* wbase = W + k0 + quad * 8;
        v8s b0 = *(const v8s*)(wbase + (size_t)(nbase +  0 + lm) * 256);
        v8s b1 = *(const v8s*)(wbase + (size_t)(nbase + 16 + lm) * 256);
        v8s b2 = *(const v8s*)(wbase + (size_t)(nbase + 32 + lm) * 256);
        v8s b3 = *(const v8s*)(wbase + (size_t)(nbase + 48 + lm) * 256);

        acc0 = __builtin_amdgcn_mfma_f32_16x16x32_bf16(af, b0, acc0, 0, 0, 0);
        acc1 = __builtin_amdgcn_mfma_f32_16x16x32_bf16(af, b1, acc1, 0, 0, 0);
        acc2 = __builtin_amdgcn_mfma_f32_16x16x32_bf16(af, b2, acc2, 0, 0, 0);
        acc3 = __builtin_amdgcn_mfma_f32_16x16x32_bf16(af, b3, acc3, 0, 0, 0);
    }

#pragma unroll
    for (int t = 0; t < 4; t++) {
        int col = nbase + t * 16 + lm;
        float bcol = bias[col];
        v4f acc = (t == 0) ? acc0 : (t == 1) ? acc1 : (t == 2) ? acc2 : acc3;
#pragma unroll
        for (int r = 0; r < 4; r++) {
            int row = mbase + quad * 4 + r;
            if (row < M) Out[(size_t)row * 256 + col] = f2bf(acc[r] + bcol);
        }
    }
}

// ------------------------------------------------------- per-edge scores
// 64 lanes per edge; raw score only (softmax handled in CSR agg kernel).
__global__ __launch_bounds__(256) void score_kernel(
    const int* __restrict__ src_idx, const int* __restrict__ dst_idx,
    const unsigned short* __restrict__ K, const unsigned short* __restrict__ Q,
    float* __restrict__ score) {

    int wave = threadIdx.x >> 6, lane = threadIdx.x & 63;
    int e = blockIdx.x * 4 + wave;
    if (e >= N_EDGES) return;
    int s = src_idx[e], d = dst_idx[e];

    ushort4 kv = *((const ushort4*)(K + (size_t)s * 256) + lane);
    ushort4 qv = *((const ushort4*)(Q + (size_t)d * 256) + lane);
    float p = bf2f(kv.x) * bf2f(qv.x) + bf2f(kv.y) * bf2f(qv.y) +
              bf2f(kv.z) * bf2f(qv.z) + bf2f(kv.w) * bf2f(qv.w);
    p += __shfl_xor(p, 1, 64);
    p += __shfl_xor(p, 2, 64);
    p += __shfl_xor(p, 4, 64);
    p += __shfl_xor(p, 8, 64);
    p *= 0.125f;                                  // 1/sqrt(64)

    if ((lane & 15) == 0) {
        score[(size_t)e * 4 + (lane >> 4)] = p;
    }
}

// ----------------------------------------------------------- CSR building
__global__ void hist_kernel(const int* __restrict__ dst_idx,
                            int* __restrict__ cnt) {
    int i = blockIdx.x * 256 + threadIdx.x;
    if (i < N_EDGES) atomicAdd(&cnt[dst_idx[i]], 1);
}

// Single-block hierarchical exclusive scan over 50000 counts.
__global__ __launch_bounds__(1024) void scan_kernel(
    const int* __restrict__ cnt, int* __restrict__ offsets,
    int* __restrict__ cursor) {
    __shared__ int lsum[1024];
    int t = threadIdx.x;
    const int CH = (N_DST + 1023) / 1024;          // 49
    int lo = t * CH, hi = min(N_DST, lo + CH);
    int s = 0;
    for (int i = lo; i < hi; i++) s += cnt[i];
    lsum[t] = s;
    __syncthreads();
    for (int off = 1; off < 1024; off <<= 1) {
        int v = (t >= off) ? lsum[t - off] : 0;
        __syncthreads();
        lsum[t] += v;
        __syncthreads();
    }
    int run = (t == 0) ? 0 : lsum[t - 1];
    for (int i = lo; i < hi; i++) {
        offsets[i] = run;
        cursor[i] = run;
        run += cnt[i];
    }
    if (t == 1023) offsets[N_DST] = N_EDGES;
}

__global__ void scatter_kernel(const int* __restrict__ src_idx,
                               const int* __restrict__ dst_idx,
                               int* __restrict__ cursor,
                               int2* __restrict__ eord) {
    int i = blockIdx.x * 256 + threadIdx.x;
    if (i >= N_EDGES) return;
    int d = dst_idx[i];
    int pos = atomicAdd(&cursor[d], 1);
    eord[pos] = make_int2(src_idx[i], i);
}

// ---------------------------- CSR aggregation with fused softmax, no atomics
// One wave per destination. lane covers output dims [lane*4, lane*4+4);
// head h = lane>>4. Three passes over the dst's edge list (avg degree 6):
// max, sum-of-exp, weighted-V accumulate. Single float4 store per lane.
__global__ __launch_bounds__(256) void agg_kernel(
    const int2* __restrict__ eord, const int* __restrict__ offsets,
    const unsigned short* __restrict__ V, const float* __restrict__ score,
    float* __restrict__ out) {

    int wave = threadIdx.x >> 6, lane = threadIdx.x & 63;
    int d = blockIdx.x * 4 + wave;
    if (d >= N_DST) return;
    int h = lane >> 4;

    int start = offsets[d], end = offsets[d + 1];

    float m = -3.0e38f;
    for (int j = start; j < end; j++) {
        int e = eord[j].y;
        m = fmaxf(m, score[(size_t)e * 4 + h]);
    }
    float ssum = 0.0f;
    for (int j = start; j < end; j++) {
        int e = eord[j].y;
        ssum += __expf(score[(size_t)e * 4 + h] - m);
    }
    float inv = 1.0f / ssum;

    float a0 = 0, a1 = 0, a2 = 0, a3 = 0;
    for (int j = start; j < end; j++) {
        int2 p = eord[j];
        float a = __expf(score[(size_t)p.y * 4 + h] - m) * inv;
        ushort4 vv = *((const ushort4*)(V + (size_t)p.x * 256) + lane);
        a0 += bf2f(vv.x) * a;
        a1 += bf2f(vv.y) * a;
        a2 += bf2f(vv.z) * a;
        a3 += bf2f(vv.w) * a;
    }
    float4 r = make_float4(a0, a1, a2, a3);
    *((float4*)(out + (size_t)d * 256) + lane) = r;
}

// --------------------------------------------------------------- launcher
extern "C" void kernel_launch(void* const* d_in, const int* in_sizes, int n_in,
                              void* d_out, int out_size, void* d_ws, size_t ws_size,
                              hipStream_t stream) {
    const float* h_src   = (const float*)d_in[0];
    const float* h_dst   = (const float*)d_in[1];
    const int*   src_idx = (const int*)d_in[2];
    const int*   dst_idx = (const int*)d_in[3];
    const float* Wq      = (const float*)d_in[4];
    const float* bq      = (const float*)d_in[5];
    const float* Wk      = (const float*)d_in[6];
    const float* bk      = (const float*)d_in[7];
    const float* Wv      = (const float*)d_in[8];
    const float* bv      = (const float*)d_in[9];
    float* out = (float*)d_out;

    // Workspace layout (256B-aligned)
    char* ws = (char*)d_ws;
    size_t off = 0;
    auto take = [&](size_t bytes) { char* p = ws + off; off = (off + bytes + 255) & ~(size_t)255; return p; };
    unsigned short* Q       = (unsigned short*)take((size_t)N_DST * 256 * 2);   // 25.6 MB
    unsigned short* K       = (unsigned short*)take((size_t)N_SRC * 256 * 2);   // 51.2 MB
    unsigned short* V       = (unsigned short*)take((size_t)N_SRC * 256 * 2);   // 51.2 MB
    unsigned short* Wb      = (unsigned short*)take((size_t)3 * 65536 * 2);     // 0.4 MB
    float*          score   = (float*)take((size_t)N_EDGES * 4 * 4);            // 4.8 MB
    int*            cnt     = (int*)take((size_t)N_DST * 4);                    // 0.2 MB
    int*            offsets = (int*)take((size_t)(N_DST + 1) * 4);              // 0.2 MB
    int*            cursor  = (int*)take((size_t)N_DST * 4);                    // 0.2 MB
    int2*           eord    = (int2*)take((size_t)N_EDGES * 8);                 // 2.4 MB
    (void)ws_size; (void)in_sizes; (void)n_in; (void)out_size;

    hipMemsetAsync(cnt, 0, (size_t)N_DST * 4, stream);

    cvt_w_kernel<<<dim3(256, 3), 256, 0, stream>>>(Wq, Wk, Wv, Wb);

    proj_kernel<<<dim3((N_SRC + 63) / 64, 4, 3), 256, 0, stream>>>(
        h_src, h_dst, Wb, bq, bk, bv, Q, K, V);

    // CSR build (independent of proj/score; cheap)
    hist_kernel<<<(N_EDGES + 255) / 256, 256, 0, stream>>>(dst_idx, cnt);
    scan_kernel<<<1, 1024, 0, stream>>>(cnt, offsets, cursor);
    scatter_kernel<<<(N_EDGES + 255) / 256, 256, 0, stream>>>(src_idx, dst_idx, cursor, eord);

    score_kernel<<<N_EDGES / 4, 256, 0, stream>>>(src_idx, dst_idx, K, Q, score);

    agg_kernel<<<(N_DST + 3) / 4, 256, 0, stream>>>(eord, offsets, V, score, out);
}

// Round 3
// 676.303 us; speedup vs baseline: 2.4057x; 1.2167x over previous
//
#include <hip/hip_runtime.h>
#include <hip/hip_bf16.h>
#include <stdint.h>

#define IN_DIM    256
#define OUT_DIM   256
#define NUM_HEADS 4
#define HEAD_DIM  64
#define N_SRC     100000
#define N_DST     50000
#define N_EDGES   300000

typedef __attribute__((ext_vector_type(8))) short v8s;   // 8 x bf16 bits
typedef __attribute__((ext_vector_type(4))) float v4f;   // MFMA accumulator

__device__ __forceinline__ unsigned short f2bf(float f) {
    unsigned u = __float_as_uint(f);
    unsigned r = (u + 0x7FFFu + ((u >> 16) & 1u)) >> 16;   // RNE
    return (unsigned short)r;
}
__device__ __forceinline__ float bf2f(unsigned short s) {
    return __uint_as_float(((unsigned)s) << 16);
}

// ---------------------------------------------------------------- W -> bf16
__global__ void cvt_w_kernel(const float* __restrict__ Wq,
                             const float* __restrict__ Wk,
                             const float* __restrict__ Wv,
                             unsigned short* __restrict__ Wb) {
    int m = blockIdx.y;
    const float* src = (m == 0) ? Wq : (m == 1) ? Wk : Wv;
    int i = blockIdx.x * 256 + threadIdx.x;   // 0..65535
    Wb[m * 65536 + i] = f2bf(src[i]);
}

// ------------------------------------------------- fused Q/K/V projections
// One wave computes a 16-row x 256-col output stripe (16 MFMA tiles) so A is
// fetched exactly once per projection. Per k-step: 2 A-loads (fp32->bf16
// inline), 16 independent B-loads, 16 MFMAs.
// A-frag: h[m=lane&15][k0 + quad*8 + j]
// B-frag: W[n=nt*16 + lane&15][k0 + quad*8 + j] (bf16, contiguous 16B)
// C/D:    col = nt*16 + lane&15, row = quad*4 + reg
__global__ __launch_bounds__(256) void proj_kernel(
    const float* __restrict__ h_src, const float* __restrict__ h_dst,
    const unsigned short* __restrict__ Wb,
    const float* __restrict__ bq, const float* __restrict__ bk,
    const float* __restrict__ bv,
    unsigned short* __restrict__ Q, unsigned short* __restrict__ K,
    unsigned short* __restrict__ V) {

    int z = blockIdx.z;
    const float* A; const unsigned short* W; const float* bias;
    unsigned short* Out; int M;
    if (z == 0)      { A = h_dst; W = Wb;           bias = bq; Out = Q; M = N_DST; }
    else if (z == 1) { A = h_src; W = Wb + 65536;   bias = bk; Out = K; M = N_SRC; }
    else             { A = h_src; W = Wb + 131072;  bias = bv; Out = V; M = N_SRC; }

    int wave = threadIdx.x >> 6;
    int lane = threadIdx.x & 63;
    int mbase = blockIdx.x * 64 + wave * 16;
    if (mbase >= M) return;
    int lm = lane & 15, quad = lane >> 4;

    int arow = mbase + lm;
    if (arow >= M) arow = M - 1;               // clamp; store is guarded
    const float* aptr = A + (size_t)arow * 256 + quad * 8;
    const unsigned short* wptr = W + (size_t)lm * 256 + quad * 8;

    v4f acc[16];
#pragma unroll
    for (int i = 0; i < 16; i++) acc[i] = (v4f){0, 0, 0, 0};

    for (int k0 = 0; k0 < 256; k0 += 32) {
        const float4* ap = (const float4*)(aptr + k0);
        float4 a0 = ap[0], a1 = ap[1];
        v8s af;
        af[0] = (short)f2bf(a0.x); af[1] = (short)f2bf(a0.y);
        af[2] = (short)f2bf(a0.z); af[3] = (short)f2bf(a0.w);
        af[4] = (short)f2bf(a1.x); af[5] = (short)f2bf(a1.y);
        af[6] = (short)f2bf(a1.z); af[7] = (short)f2bf(a1.w);

        const unsigned short* wb = wptr + k0;
#pragma unroll
        for (int nt = 0; nt < 16; nt++) {
            v8s bf = *(const v8s*)(wb + (size_t)nt * 16 * 256);
            acc[nt] = __builtin_amdgcn_mfma_f32_16x16x32_bf16(af, bf, acc[nt], 0, 0, 0);
        }
    }

    bool full = (mbase + 15 < M);
#pragma unroll
    for (int nt = 0; nt < 16; nt++) {
        int col = nt * 16 + lm;
        float bcol = bias[col];
#pragma unroll
        for (int r = 0; r < 4; r++) {
            int row = mbase + quad * 4 + r;
            if (full || row < M)
                Out[(size_t)row * 256 + col] = f2bf(acc[nt][r] + bcol);
        }
    }
}

// ----------------------------------------------------------- CSR building
__global__ void hist_kernel(const int* __restrict__ dst_idx,
                            int* __restrict__ cnt) {
    int i = blockIdx.x * 256 + threadIdx.x;
    if (i < N_EDGES) atomicAdd(&cnt[dst_idx[i]], 1);
}

// Single-block hierarchical exclusive scan over 50000 counts.
__global__ __launch_bounds__(1024) void scan_kernel(
    const int* __restrict__ cnt, int* __restrict__ offsets,
    int* __restrict__ cursor) {
    __shared__ int lsum[1024];
    int t = threadIdx.x;
    const int CH = (N_DST + 1023) / 1024;          // 49
    int lo = t * CH, hi = min(N_DST, lo + CH);
    int s = 0;
    for (int i = lo; i < hi; i++) s += cnt[i];
    lsum[t] = s;
    __syncthreads();
    for (int off = 1; off < 1024; off <<= 1) {
        int v = (t >= off) ? lsum[t - off] : 0;
        __syncthreads();
        lsum[t] += v;
        __syncthreads();
    }
    int run = (t == 0) ? 0 : lsum[t - 1];
    for (int i = lo; i < hi; i++) {
        offsets[i] = run;
        cursor[i] = run;
        run += cnt[i];
    }
    if (t == 1023) offsets[N_DST] = N_EDGES;
}

__global__ void scatter_kernel(const int* __restrict__ src_idx,
                               const int* __restrict__ dst_idx,
                               int* __restrict__ cursor,
                               int* __restrict__ esrc) {
    int i = blockIdx.x * 256 + threadIdx.x;
    if (i >= N_EDGES) return;
    int d = dst_idx[i];
    int pos = atomicAdd(&cursor[d], 1);
    esrc[pos] = src_idx[i];
}

// -------------- fused score + online-softmax + aggregation (one wave/dst)
// Q[d] loaded once per dst. Per edge: gather K and V rows (512B each, L3),
// dot via 4 shfl-xors within each 16-lane head group, flash-style m/l
// rescale, accumulate a*V in registers. One float4 store per lane.
__global__ __launch_bounds__(256) void agg_kernel(
    const int* __restrict__ esrc, const int* __restrict__ offsets,
    const unsigned short* __restrict__ Q, const unsigned short* __restrict__ K,
    const unsigned short* __restrict__ V, float* __restrict__ out) {

    int wave = threadIdx.x >> 6, lane = threadIdx.x & 63;
    int d = blockIdx.x * 4 + wave;
    if (d >= N_DST) return;

    int start = offsets[d], end = offsets[d + 1];
    float4 o = make_float4(0.f, 0.f, 0.f, 0.f);

    if (end > start) {
        ushort4 qv = *((const ushort4*)(Q + (size_t)d * 256) + lane);
        float q0 = bf2f(qv.x), q1 = bf2f(qv.y), q2 = bf2f(qv.z), q3 = bf2f(qv.w);

        float m = -3.0e38f, l = 0.f;
        float a0 = 0.f, a1 = 0.f, a2 = 0.f, a3 = 0.f;

        int s_next = esrc[start];
        for (int j = start; j < end; j++) {
            int s = s_next;
            if (j + 1 < end) s_next = esrc[j + 1];
            ushort4 kv = *((const ushort4*)(K + (size_t)s * 256) + lane);
            ushort4 vv = *((const ushort4*)(V + (size_t)s * 256) + lane);

            float p = bf2f(kv.x) * q0 + bf2f(kv.y) * q1 +
                      bf2f(kv.z) * q2 + bf2f(kv.w) * q3;
            p += __shfl_xor(p, 1, 64);
            p += __shfl_xor(p, 2, 64);
            p += __shfl_xor(p, 4, 64);
            p += __shfl_xor(p, 8, 64);
            p *= 0.125f;                           // 1/sqrt(64)

            float mn = fmaxf(m, p);
            float sc = __expf(m - mn);             // first iter: exp(-huge)=0
            float w  = __expf(p - mn);
            l = l * sc + w;
            a0 = a0 * sc + w * bf2f(vv.x);
            a1 = a1 * sc + w * bf2f(vv.y);
            a2 = a2 * sc + w * bf2f(vv.z);
            a3 = a3 * sc + w * bf2f(vv.w);
            m = mn;
        }
        float inv = 1.0f / l;
        o = make_float4(a0 * inv, a1 * inv, a2 * inv, a3 * inv);
    }
    *((float4*)(out + (size_t)d * 256) + lane) = o;   // empty dst -> zeros
}

// --------------------------------------------------------------- launcher
extern "C" void kernel_launch(void* const* d_in, const int* in_sizes, int n_in,
                              void* d_out, int out_size, void* d_ws, size_t ws_size,
                              hipStream_t stream) {
    const float* h_src   = (const float*)d_in[0];
    const float* h_dst   = (const float*)d_in[1];
    const int*   src_idx = (const int*)d_in[2];
    const int*   dst_idx = (const int*)d_in[3];
    const float* Wq      = (const float*)d_in[4];
    const float* bq      = (const float*)d_in[5];
    const float* Wk      = (const float*)d_in[6];
    const float* bk      = (const float*)d_in[7];
    const float* Wv      = (const float*)d_in[8];
    const float* bv      = (const float*)d_in[9];
    float* out = (float*)d_out;

    // Workspace layout (256B-aligned)
    char* ws = (char*)d_ws;
    size_t off = 0;
    auto take = [&](size_t bytes) { char* p = ws + off; off = (off + bytes + 255) & ~(size_t)255; return p; };
    unsigned short* Q       = (unsigned short*)take((size_t)N_DST * 256 * 2);   // 25.6 MB
    unsigned short* K       = (unsigned short*)take((size_t)N_SRC * 256 * 2);   // 51.2 MB
    unsigned short* V       = (unsigned short*)take((size_t)N_SRC * 256 * 2);   // 51.2 MB
    unsigned short* Wb      = (unsigned short*)take((size_t)3 * 65536 * 2);     // 0.4 MB
    int*            cnt     = (int*)take((size_t)N_DST * 4);                    // 0.2 MB
    int*            offsets = (int*)take((size_t)(N_DST + 1) * 4);              // 0.2 MB
    int*            cursor  = (int*)take((size_t)N_DST * 4);                    // 0.2 MB
    int*            esrc    = (int*)take((size_t)N_EDGES * 4);                  // 1.2 MB
    (void)ws_size; (void)in_sizes; (void)n_in; (void)out_size;

    hipMemsetAsync(cnt, 0, (size_t)N_DST * 4, stream);

    cvt_w_kernel<<<dim3(256, 3), 256, 0, stream>>>(Wq, Wk, Wv, Wb);

    // CSR build (independent of proj; cheap)
    hist_kernel<<<(N_EDGES + 255) / 256, 256, 0, stream>>>(dst_idx, cnt);
    scan_kernel<<<1, 1024, 0, stream>>>(cnt, offsets, cursor);
    scatter_kernel<<<(N_EDGES + 255) / 256, 256, 0, stream>>>(src_idx, dst_idx, cursor, esrc);

    // 64 rows per block (4 waves x 16 rows), full 256 cols per wave
    proj_kernel<<<dim3((N_SRC + 63) / 64, 1, 3), 256, 0, stream>>>(
        h_src, h_dst, Wb, bq, bk, bv, Q, K, V);

    agg_kernel<<<(N_DST + 3) / 4, 256, 0, stream>>>(esrc, offsets, Q, K, V, out);
}

// Round 4
// 525.312 us; speedup vs baseline: 3.0971x; 1.2874x over previous
//
#include <hip/hip_runtime.h>
#include <hip/hip_bf16.h>
#include <stdint.h>

#define IN_DIM    256
#define OUT_DIM   256
#define NUM_HEADS 4
#define HEAD_DIM  64
#define N_SRC     100000
#define N_DST     50000
#define N_EDGES   300000

#define BM 128
#define BN 128
#define BK 32

typedef __attribute__((ext_vector_type(8))) short v8s;   // 8 x bf16 bits
typedef __attribute__((ext_vector_type(4))) float v4f;   // MFMA accumulator

__device__ __forceinline__ unsigned short f2bf(float f) {
    unsigned u = __float_as_uint(f);
    unsigned r = (u + 0x7FFFu + ((u >> 16) & 1u)) >> 16;   // RNE
    return (unsigned short)r;
}
__device__ __forceinline__ float bf2f(unsigned short s) {
    return __uint_as_float(((unsigned)s) << 16);
}

// async global->LDS, 16B per lane; lds base is wave-uniform, lane i deposits
// at base + i*16 (guide §5: width=16 variant, global_load_lds_dwordx4)
__device__ __forceinline__ void async_copy16(const unsigned short* g,
                                             unsigned short* l) {
    __builtin_amdgcn_global_load_lds(
        (const __attribute__((address_space(1))) unsigned int*)g,
        (__attribute__((address_space(3))) unsigned int*)l, 16, 0, 0);
}

// ------------------------------------------------------------ fp32 -> bf16
__global__ void cvt_kernel(const float* __restrict__ src,
                           unsigned short* __restrict__ dst, int n8) {
    int i = blockIdx.x * 256 + threadIdx.x;
    if (i >= n8) return;
    const float4* s = (const float4*)(src + (size_t)i * 8);
    float4 x = s[0], y = s[1];
    v8s o;
    o[0] = (short)f2bf(x.x); o[1] = (short)f2bf(x.y);
    o[2] = (short)f2bf(x.z); o[3] = (short)f2bf(x.w);
    o[4] = (short)f2bf(y.x); o[5] = (short)f2bf(y.y);
    o[6] = (short)f2bf(y.z); o[7] = (short)f2bf(y.w);
    *(v8s*)(dst + (size_t)i * 8) = o;
}

// ---------------------------- tiled GEMM (m97 structure): Out = A @ W^T + b
// A: [M][256] bf16 row-major. W: [256][256] bf16 row-major [n][k] (== B^T).
// 128x128 tile, BK=32, double-buffered LDS, global_load_lds staging.
// 4 waves in 2x2 quadrants; each wave: 4x4 16x16 acc tiles, 16 MFMA +
// 8 ds_read_b128 per k-step.
__global__ __launch_bounds__(256) void gemm_kernel(
    const unsigned short* __restrict__ Hb_src,
    const unsigned short* __restrict__ Hb_dst,
    const unsigned short* __restrict__ Wb,
    const float* __restrict__ bq, const float* __restrict__ bk,
    const float* __restrict__ bv,
    unsigned short* __restrict__ Q, unsigned short* __restrict__ K,
    unsigned short* __restrict__ V) {

    __shared__ unsigned short sA[2][BM][BK];   // 8 KB per buffer
    __shared__ unsigned short sB[2][BN][BK];   // 8 KB per buffer

    int z = blockIdx.z;
    const unsigned short* A; const unsigned short* W;
    const float* bias; unsigned short* Out; int M;
    if (z == 0)      { A = Hb_dst; W = Wb;          bias = bq; Out = Q; M = N_DST; }
    else if (z == 1) { A = Hb_src; W = Wb + 65536;  bias = bk; Out = K; M = N_SRC; }
    else             { A = Hb_src; W = Wb + 131072; bias = bv; Out = V; M = N_SRC; }

    int mbase = blockIdx.x * BM;
    if (mbase >= M) return;                    // z==0 tail blocks
    int nbase = blockIdx.y * BN;

    int wave = threadIdx.x >> 6;
    int lane = threadIdx.x & 63;
    int lm = lane & 15, quad = lane >> 4;

    // staging coords: lane l -> row l/4, kchunk (l&3)*8 within a 16-row slab
    int sr = lane >> 2;
    int skc = (lane & 3) * 8;

    // per-lane global source addresses (row clamped to M-1; stores guarded)
    int ga0 = mbase + wave * 32 + sr;       if (ga0 > M - 1) ga0 = M - 1;
    int ga1 = mbase + wave * 32 + 16 + sr;  if (ga1 > M - 1) ga1 = M - 1;
    const unsigned short* gA0 = A + (size_t)ga0 * 256 + skc;
    const unsigned short* gA1 = A + (size_t)ga1 * 256 + skc;
    const unsigned short* gB0 = W + (size_t)(nbase + wave * 32 + sr) * 256 + skc;
    const unsigned short* gB1 = W + (size_t)(nbase + wave * 32 + 16 + sr) * 256 + skc;

    v4f acc[4][4];
#pragma unroll
    for (int i = 0; i < 4; i++)
#pragma unroll
        for (int j = 0; j < 4; j++) acc[i][j] = (v4f){0, 0, 0, 0};

    int wr = (wave >> 1) * 64;   // quadrant row base
    int wc = (wave & 1) * 64;    // quadrant col base

    // prologue: stage k0=0 into buf 0
    async_copy16(gA0, &sA[0][wave * 32][0]);
    async_copy16(gA1, &sA[0][wave * 32 + 16][0]);
    async_copy16(gB0, &sB[0][wave * 32][0]);
    async_copy16(gB1, &sB[0][wave * 32 + 16][0]);
    __syncthreads();

    const int NK = 256 / BK;                   // 8
    int buf = 0;
#pragma unroll
    for (int ks = 0; ks < NK; ks++) {
        if (ks + 1 < NK) {
            int k0 = (ks + 1) * BK;
            async_copy16(gA0 + k0, &sA[buf ^ 1][wave * 32][0]);
            async_copy16(gA1 + k0, &sA[buf ^ 1][wave * 32 + 16][0]);
            async_copy16(gB0 + k0, &sB[buf ^ 1][wave * 32][0]);
            async_copy16(gB1 + k0, &sB[buf ^ 1][wave * 32 + 16][0]);
        }

        v8s af[4], bf[4];
#pragma unroll
        for (int i = 0; i < 4; i++)
            af[i] = *(const v8s*)&sA[buf][wr + i * 16 + lm][quad * 8];
#pragma unroll
        for (int j = 0; j < 4; j++)
            bf[j] = *(const v8s*)&sB[buf][wc + j * 16 + lm][quad * 8];
#pragma unroll
        for (int i = 0; i < 4; i++)
#pragma unroll
            for (int j = 0; j < 4; j++)
                acc[i][j] = __builtin_amdgcn_mfma_f32_16x16x32_bf16(
                    af[i], bf[j], acc[i][j], 0, 0, 0);

        buf ^= 1;
        __syncthreads();
    }

    // epilogue: bias + cvt + store (C/D: col=lane&15, row=quad*4+r)
    bool full = (mbase + BM <= M);
#pragma unroll
    for (int j = 0; j < 4; j++) {
        int col = nbase + wc + j * 16 + lm;
        float bcol = bias[col];
#pragma unroll
        for (int i = 0; i < 4; i++) {
#pragma unroll
            for (int r = 0; r < 4; r++) {
                int row = mbase + wr + i * 16 + quad * 4 + r;
                if (full || row < M)
                    Out[(size_t)row * 256 + col] = f2bf(acc[i][j][r] + bcol);
            }
        }
    }
}

// ----------------------------------------------------------- CSR building
__global__ void hist_kernel(const int* __restrict__ dst_idx,
                            int* __restrict__ cnt) {
    int i = blockIdx.x * 256 + threadIdx.x;
    if (i < N_EDGES) atomicAdd(&cnt[dst_idx[i]], 1);
}

// Single-block hierarchical exclusive scan over 50000 counts.
__global__ __launch_bounds__(1024) void scan_kernel(
    const int* __restrict__ cnt, int* __restrict__ offsets,
    int* __restrict__ cursor) {
    __shared__ int lsum[1024];
    int t = threadIdx.x;
    const int CH = (N_DST + 1023) / 1024;          // 49
    int lo = t * CH, hi = min(N_DST, lo + CH);
    int s = 0;
    for (int i = lo; i < hi; i++) s += cnt[i];
    lsum[t] = s;
    __syncthreads();
    for (int off = 1; off < 1024; off <<= 1) {
        int v = (t >= off) ? lsum[t - off] : 0;
        __syncthreads();
        lsum[t] += v;
        __syncthreads();
    }
    int run = (t == 0) ? 0 : lsum[t - 1];
    for (int i = lo; i < hi; i++) {
        offsets[i] = run;
        cursor[i] = run;
        run += cnt[i];
    }
    if (t == 1023) offsets[N_DST] = N_EDGES;
}

__global__ void scatter_kernel(const int* __restrict__ src_idx,
                               const int* __restrict__ dst_idx,
                               int* __restrict__ cursor,
                               int* __restrict__ esrc) {
    int i = blockIdx.x * 256 + threadIdx.x;
    if (i >= N_EDGES) return;
    int d = dst_idx[i];
    int pos = atomicAdd(&cursor[d], 1);
    esrc[pos] = src_idx[i];
}

// -------------- fused score + online-softmax + aggregation (one wave/dst)
__global__ __launch_bounds__(256) void agg_kernel(
    const int* __restrict__ esrc, const int* __restrict__ offsets,
    const unsigned short* __restrict__ Q, const unsigned short* __restrict__ K,
    const unsigned short* __restrict__ V, float* __restrict__ out) {

    int wave = threadIdx.x >> 6, lane = threadIdx.x & 63;
    int d = blockIdx.x * 4 + wave;
    if (d >= N_DST) return;

    int start = offsets[d], end = offsets[d + 1];
    float4 o = make_float4(0.f, 0.f, 0.f, 0.f);

    if (end > start) {
        ushort4 qv = *((const ushort4*)(Q + (size_t)d * 256) + lane);
        float q0 = bf2f(qv.x), q1 = bf2f(qv.y), q2 = bf2f(qv.z), q3 = bf2f(qv.w);

        float m = -3.0e38f, l = 0.f;
        float a0 = 0.f, a1 = 0.f, a2 = 0.f, a3 = 0.f;

        int s_next = esrc[start];
        for (int j = start; j < end; j++) {
            int s = s_next;
            if (j + 1 < end) s_next = esrc[j + 1];
            ushort4 kv = *((const ushort4*)(K + (size_t)s * 256) + lane);
            ushort4 vv = *((const ushort4*)(V + (size_t)s * 256) + lane);

            float p = bf2f(kv.x) * q0 + bf2f(kv.y) * q1 +
                      bf2f(kv.z) * q2 + bf2f(kv.w) * q3;
            p += __shfl_xor(p, 1, 64);
            p += __shfl_xor(p, 2, 64);
            p += __shfl_xor(p, 4, 64);
            p += __shfl_xor(p, 8, 64);
            p *= 0.125f;                           // 1/sqrt(64)

            float mn = fmaxf(m, p);
            float sc = __expf(m - mn);             // first iter: exp(-huge)=0
            float w  = __expf(p - mn);
            l = l * sc + w;
            a0 = a0 * sc + w * bf2f(vv.x);
            a1 = a1 * sc + w * bf2f(vv.y);
            a2 = a2 * sc + w * bf2f(vv.z);
            a3 = a3 * sc + w * bf2f(vv.w);
            m = mn;
        }
        float inv = 1.0f / l;
        o = make_float4(a0 * inv, a1 * inv, a2 * inv, a3 * inv);
    }
    *((float4*)(out + (size_t)d * 256) + lane) = o;   // empty dst -> zeros
}

// --------------------------------------------------------------- launcher
extern "C" void kernel_launch(void* const* d_in, const int* in_sizes, int n_in,
                              void* d_out, int out_size, void* d_ws, size_t ws_size,
                              hipStream_t stream) {
    const float* h_src   = (const float*)d_in[0];
    const float* h_dst   = (const float*)d_in[1];
    const int*   src_idx = (const int*)d_in[2];
    const int*   dst_idx = (const int*)d_in[3];
    const float* Wq      = (const float*)d_in[4];
    const float* bq      = (const float*)d_in[5];
    const float* Wk      = (const float*)d_in[6];
    const float* bk      = (const float*)d_in[7];
    const float* Wv      = (const float*)d_in[8];
    const float* bv      = (const float*)d_in[9];
    float* out = (float*)d_out;

    // Workspace layout (256B-aligned)
    char* ws = (char*)d_ws;
    size_t off = 0;
    auto take = [&](size_t bytes) { char* p = ws + off; off = (off + bytes + 255) & ~(size_t)255; return p; };
    unsigned short* Hb_src  = (unsigned short*)take((size_t)N_SRC * 256 * 2);   // 51.2 MB
    unsigned short* Hb_dst  = (unsigned short*)take((size_t)N_DST * 256 * 2);   // 25.6 MB
    unsigned short* Q       = (unsigned short*)take((size_t)N_DST * 256 * 2);   // 25.6 MB
    unsigned short* K       = (unsigned short*)take((size_t)N_SRC * 256 * 2);   // 51.2 MB
    unsigned short* V       = (unsigned short*)take((size_t)N_SRC * 256 * 2);   // 51.2 MB
    unsigned short* Wb      = (unsigned short*)take((size_t)3 * 65536 * 2);     // 0.4 MB
    int*            cnt     = (int*)take((size_t)N_DST * 4);                    // 0.2 MB
    int*            offsets = (int*)take((size_t)(N_DST + 1) * 4);              // 0.2 MB
    int*            cursor  = (int*)take((size_t)N_DST * 4);                    // 0.2 MB
    int*            esrc    = (int*)take((size_t)N_EDGES * 4);                  // 1.2 MB
    (void)ws_size; (void)in_sizes; (void)n_in; (void)out_size;

    hipMemsetAsync(cnt, 0, (size_t)N_DST * 4, stream);

    // fp32 -> bf16 conversions
    {
        int n8s = N_SRC * 256 / 8, n8d = N_DST * 256 / 8, n8w = 65536 / 8;
        cvt_kernel<<<(n8s + 255) / 256, 256, 0, stream>>>(h_src, Hb_src, n8s);
        cvt_kernel<<<(n8d + 255) / 256, 256, 0, stream>>>(h_dst, Hb_dst, n8d);
        cvt_kernel<<<(n8w + 255) / 256, 256, 0, stream>>>(Wq, Wb, n8w);
        cvt_kernel<<<(n8w + 255) / 256, 256, 0, stream>>>(Wk, Wb + 65536, n8w);
        cvt_kernel<<<(n8w + 255) / 256, 256, 0, stream>>>(Wv, Wb + 131072, n8w);
    }

    // CSR build (independent of proj; cheap)
    hist_kernel<<<(N_EDGES + 255) / 256, 256, 0, stream>>>(dst_idx, cnt);
    scan_kernel<<<1, 1024, 0, stream>>>(cnt, offsets, cursor);
    scatter_kernel<<<(N_EDGES + 255) / 256, 256, 0, stream>>>(src_idx, dst_idx, cursor, esrc);

    // Q/K/V projections: 128x128 tiles, x covers max(M)=N_SRC
    gemm_kernel<<<dim3((N_SRC + BM - 1) / BM, 256 / BN, 3), 256, 0, stream>>>(
        Hb_src, Hb_dst, Wb, bq, bk, bv, Q, K, V);

    agg_kernel<<<(N_DST + 3) / 4, 256, 0, stream>>>(esrc, offsets, Q, K, V, out);
}